// Round 1
// baseline (2444.275 us; speedup 1.0000x reference)
//
#include <hip/hip_runtime.h>

#define BATCH 256
#define SEQ 2048
#define NT 48
#define START_TAG 46
#define END_TAG 47

typedef float v2f __attribute__((ext_vector_type(2)));
typedef float v4f __attribute__((ext_vector_type(4)));

#define LN2f 0.6931471805599453f

// One wave (64 lanes) per batch sample. lane = "next tag" (48 active,
// lanes 48-63 mirror lanes 32-47 so every lane does valid work / addrs).
// State h[j] ~ exp(alpha[j] - C), C tracked in log2 units.
// Per step: h'[next] = dot(E[next,:], h) * exp(emit[next]) / h[0],
//           C += log2(h[0]).
// Broadcast of h across lanes via tiny LDS buffer (single-wave block:
// DS ops are in-order within a wave, no barrier needed).
__global__ void crf_fwd(const float* __restrict__ features,
                        const float* __restrict__ transitions,
                        const int* __restrict__ seq_len,
                        float* __restrict__ out)
{
    const int b = blockIdx.x;
    const int lane = threadIdx.x;
    const int j = (lane < NT) ? lane : (lane - 16);   // tag row for this lane

    __shared__ v4f hs4[NT / 4];          // 48 floats: current h vector
    float* hs = (float*)hs4;

    // ---- E row for this lane: E[j][k] = exp(trans[j*NT+k]), as 24 f32 pairs
    v2f E2[NT / 2];
    {
        const v4f* trow = (const v4f*)(transitions + j * NT);  // 192B-aligned
        #pragma unroll
        for (int k = 0; k < NT / 4; ++k) {
            v4f tv = trow[k];
            E2[2 * k].x     = __expf(tv.x);
            E2[2 * k].y     = __expf(tv.y);
            E2[2 * k + 1].x = __expf(tv.z);
            E2[2 * k + 1].y = __expf(tv.w);
        }
    }
    const float Eend = __expf(transitions[END_TAG * NT + j]);

    const int L = seq_len[b];
    const float* fbase = features + ((size_t)b * SEQ) * NT + j;

    // ---- seed: alpha_1[j] = trans[j][START] + feat[b,0,j]
    //      h_1[j] = E[j][START] * exp(feat0)   (START_TAG=46 -> pair 23, .x)
    float q = E2[START_TAG / 2].x * __expf(fbase[0]);
    float Clog2 = 0.0f;
    if (lane < NT) hs[lane] = q;

    // ---- emission prefetch pipeline, depth 8 (static indices only)
    float fb[8];
    #pragma unroll
    for (int u = 0; u < 8; ++u) {
        int tp = 1 + u;
        fb[u] = fbase[(size_t)(tp < SEQ ? tp : 0) * NT];
    }

    auto STEP = [&](float femit) {
        v4f hq[NT / 4];
        #pragma unroll
        for (int k = 0; k < NT / 4; ++k) hq[k] = hs4[k];   // broadcast reads
        float h0 = hq[0].x;
        float r  = __builtin_amdgcn_rcpf(h0);              // off dot path
        float e  = __expf(femit);                          // off dot path
        v2f a0 = {0.f, 0.f}, a1 = {0.f, 0.f};
        #pragma unroll
        for (int k = 0; k < NT / 4; ++k) {
            v2f lo = { hq[k].x, hq[k].y };
            v2f hi = { hq[k].z, hq[k].w };
            a0 += E2[2 * k]     * lo;                      // hope: v_pk_fma_f32
            a1 += E2[2 * k + 1] * hi;
        }
        float d = (a0.x + a1.x) + (a0.y + a1.y);
        q = d * r * e;
        Clog2 += __log2f(h0);                              // off critical path
        if (lane < NT) hs[lane] = q;
    };

    // ---- main loop t = 1 .. L-1, unrolled x8 with rolling prefetch
    int t = 1;
    while (t + 8 <= L) {
        #pragma unroll
        for (int u = 0; u < 8; ++u) {
            STEP(fb[u]);
            int tp = t + u + 8;
            fb[u] = fbase[(size_t)(tp < SEQ ? tp : 0) * NT];  // for next chunk
        }
        t += 8;
    }
    #pragma unroll
    for (int u = 0; u < 8; ++u) {           // tail (<8 steps), static fb index
        if (t + u < L) STEP(fb[u]);
    }

    // ---- terminal: out[b] = ln2 * (C + log2( sum_j h_L[j] * Eend[j] ))
    float term = (lane < NT) ? q * Eend : 0.0f;
    #pragma unroll
    for (int m = 32; m >= 1; m >>= 1)
        term += __shfl_xor(term, m, 64);
    if (lane == 0)
        out[b] = LN2f * (Clog2 + __log2f(term));
}

extern "C" void kernel_launch(void* const* d_in, const int* in_sizes, int n_in,
                              void* d_out, int out_size, void* d_ws, size_t ws_size,
                              hipStream_t stream) {
    const float* features    = (const float*)d_in[0];
    const float* transitions = (const float*)d_in[1];
    const int*   seqlen      = (const int*)d_in[2];
    float* out = (float*)d_out;
    crf_fwd<<<BATCH, 64, 0, stream>>>(features, transitions, seqlen, out);
}

// Round 2
// 354.040 us; speedup vs baseline: 6.9040x; 6.9040x over previous
//
#include <hip/hip_runtime.h>

#define BATCH 256
#define SEQ 2048
#define NT 48
#define START_TAG 46
#define END_TAG 47

typedef float v2f __attribute__((ext_vector_type(2)));
typedef float v4f __attribute__((ext_vector_type(4)));

#define LN2f 0.6931471805599453f

// One wave (64 lanes) per batch sample. lane = "next tag" (48 active,
// lanes 48-63 mirror lanes 32-47 so every lane does valid work / addrs).
// State h[j] ~ exp(alpha[j] - C), C tracked in log2 units.
// Per step: h'[next] = dot(E[next,:], h) * exp(emit[next]) / h[0],
//           C += log2(h[0]).
// Broadcast of h across lanes via tiny LDS buffer (single-wave block:
// DS ops are in-order within a wave, no barrier needed).
//
// __launch_bounds__(64): 1 wave per workgroup -> VGPR budget up to 512.
// Without it the backend capped at 64 VGPRs and spilled E2/hq to scratch
// (round-1 counters: VGPR_Count=64, 3240 cyc/step).
__global__ void __launch_bounds__(64)
crf_fwd(const float* __restrict__ features,
        const float* __restrict__ transitions,
        const int* __restrict__ seq_len,
        float* __restrict__ out)
{
    const int b = blockIdx.x;
    const int lane = threadIdx.x;
    const int j = (lane < NT) ? lane : (lane - 16);   // tag row for this lane

    __shared__ v4f hs4[NT / 4];          // 48 floats: current h vector
    float* hs = (float*)hs4;

    // ---- E row for this lane: E[j][k] = exp(trans[j*NT+k]), as 24 f32 pairs
    v2f E2[NT / 2];
    {
        const v4f* trow = (const v4f*)(transitions + j * NT);  // 192B-aligned
        #pragma unroll
        for (int k = 0; k < NT / 4; ++k) {
            v4f tv = trow[k];
            E2[2 * k].x     = __expf(tv.x);
            E2[2 * k].y     = __expf(tv.y);
            E2[2 * k + 1].x = __expf(tv.z);
            E2[2 * k + 1].y = __expf(tv.w);
        }
    }
    const float Eend = __expf(transitions[END_TAG * NT + j]);

    const int L = seq_len[b];
    const float* fbase = features + ((size_t)b * SEQ) * NT + j;

    // ---- seed: alpha_1[j] = trans[j][START] + feat[b,0,j]
    //      h_1[j] = E[j][START] * exp(feat0)   (START_TAG=46 -> pair 23, .x)
    float q = E2[START_TAG / 2].x * __expf(fbase[0]);
    float Clog2 = 0.0f;
    if (lane < NT) hs[lane] = q;

    // ---- emission prefetch pipeline, depth 8 (static indices only)
    float fb[8];
    #pragma unroll
    for (int u = 0; u < 8; ++u) {
        int tp = 1 + u;
        fb[u] = fbase[(size_t)(tp < SEQ ? tp : 0) * NT];
    }

    auto STEP = [&](float femit) {
        v4f hq[NT / 4];
        #pragma unroll
        for (int k = 0; k < NT / 4; ++k) hq[k] = hs4[k];   // broadcast reads
        float h0 = hq[0].x;
        float r  = __builtin_amdgcn_rcpf(h0);              // off dot path
        float e  = __expf(femit);                          // off dot path
        float re = r * e;                                  // off dot path
        v2f a0 = {0.f, 0.f}, a1 = {0.f, 0.f};
        #pragma unroll
        for (int k = 0; k < NT / 4; ++k) {
            v2f lo = { hq[k].x, hq[k].y };
            v2f hi = { hq[k].z, hq[k].w };
            a0 += E2[2 * k]     * lo;                      // v_pk_fma_f32
            a1 += E2[2 * k + 1] * hi;
        }
        float d = (a0.x + a1.x) + (a0.y + a1.y);
        q = d * re;
        Clog2 += __log2f(h0);                              // off critical path
        if (lane < NT) hs[lane] = q;
    };

    // ---- main loop t = 1 .. L-1, unrolled x8 with rolling prefetch
    int t = 1;
    while (t + 8 <= L) {
        #pragma unroll
        for (int u = 0; u < 8; ++u) {
            STEP(fb[u]);
            int tp = t + u + 8;
            fb[u] = fbase[(size_t)(tp < SEQ ? tp : 0) * NT];  // for next chunk
        }
        t += 8;
    }
    #pragma unroll
    for (int u = 0; u < 8; ++u) {           // tail (<8 steps), static fb index
        if (t + u < L) STEP(fb[u]);
    }

    // ---- terminal: out[b] = ln2 * (C + log2( sum_j h_L[j] * Eend[j] ))
    float term = (lane < NT) ? q * Eend : 0.0f;
    #pragma unroll
    for (int m = 32; m >= 1; m >>= 1)
        term += __shfl_xor(term, m, 64);
    if (lane == 0)
        out[b] = LN2f * (Clog2 + __log2f(term));
}

extern "C" void kernel_launch(void* const* d_in, const int* in_sizes, int n_in,
                              void* d_out, int out_size, void* d_ws, size_t ws_size,
                              hipStream_t stream) {
    const float* features    = (const float*)d_in[0];
    const float* transitions = (const float*)d_in[1];
    const int*   seqlen      = (const int*)d_in[2];
    float* out = (float*)d_out;
    crf_fwd<<<BATCH, 64, 0, stream>>>(features, transitions, seqlen, out);
}

// Round 3
// 182.497 us; speedup vs baseline: 13.3935x; 1.9400x over previous
//
#include <hip/hip_runtime.h>

#define BATCH 256
#define SEQ 2048
#define NT 48
#define START_TAG 46
#define END_TAG 47

#define NCH 32      // chunks per sample
#define LCH 64      // steps per chunk
#define LN2f 0.6931471805599453f

// ws layout
#define TAF 0         // A-frags of exp(trans): [9 tiles][64 lanes] x 8B  (4608 B)
#define TBF 4608      // B-frag-layout exp(trans) f32: [9][64] x 16B     (9216 B)
#define TSC 16384     // per-chunk log2 scales: [B][NCH] f32             (32 KiB)
#define TW  65536     // chunk matrices M^T bf16: [B][NCH][48][48]       (37.75 MB)

typedef float v2f __attribute__((ext_vector_type(2)));
typedef float v4f __attribute__((ext_vector_type(4)));
typedef short s16x4 __attribute__((ext_vector_type(4)));
typedef unsigned int u32;
typedef u32 u32x2 __attribute__((ext_vector_type(2)));
typedef u32 u32x4 __attribute__((ext_vector_type(4)));

__device__ __forceinline__ u32 pkbf(float a, float b) {
    u32 r;
    asm("v_cvt_pk_bf16_f32 %0, %1, %2" : "=v"(r) : "v"(a), "v"(b));
    return r;
}

__device__ __forceinline__ float rfl(float x) {
    return __builtin_bit_cast(float,
        __builtin_amdgcn_readfirstlane(__builtin_bit_cast(int, x)));
}

#if defined(__has_builtin)
#if __has_builtin(__builtin_amdgcn_mfma_f32_16x16x16bf16_1k)
#define MFMA1K 1
#endif
#endif

__device__ __forceinline__ v4f mfma16(s16x4 a, s16x4 b, v4f c) {
#ifdef MFMA1K
    return __builtin_amdgcn_mfma_f32_16x16x16bf16_1k(a, b, c, 0, 0, 0);
#else
    v4f d;
    asm volatile("v_mfma_f32_16x16x16_bf16 %0, %1, %2, %3\n\ts_nop 7\n\ts_nop 7"
                 : "=v"(d) : "v"(a), "v"(b), "v"(c));
    return d;
#endif
}

// ---------------------------------------------------------------------------
// Kernel 0: build exp(trans) fragments once. 1 block x 64 (one wave).
// A-frag (tile I,K): lane holds E[I*16+(l&15)][K*16+(l>>4)*4 + i], i=0..3, bf16.
// B-frag (tile K,J): lane holds E[K*16+(l>>4)*4+i][J*16+(l&15)], f32 (scaled at
// chunk init by exp(emit) then cvt to bf16).
// ---------------------------------------------------------------------------
__global__ void __launch_bounds__(64)
crf_setup(const float* __restrict__ trans, void* ws) {
    __shared__ float el[NT * NT];
    const int lane = threadIdx.x, ln = lane & 15, g = lane >> 4;
    #pragma unroll
    for (int m = 0; m < 36; ++m) {
        int idx = lane + 64 * m;
        el[idx] = __expf(trans[idx]);
    }
    u32x2* AF = (u32x2*)((char*)ws + TAF);
    v4f*   BF = (v4f*)((char*)ws + TBF);
    #pragma unroll
    for (int I = 0; I < 3; ++I)
        #pragma unroll
        for (int K = 0; K < 3; ++K) {
            const v4f ev = *(const v4f*)&el[(I * 16 + ln) * NT + K * 16 + g * 4];
            u32x2 w;
            w.x = pkbf(ev.x, ev.y);
            w.y = pkbf(ev.z, ev.w);
            AF[(I * 3 + K) * 64 + lane] = w;
        }
    #pragma unroll
    for (int K = 0; K < 3; ++K)
        #pragma unroll
        for (int J = 0; J < 3; ++J) {
            v4f v;
            #pragma unroll
            for (int i = 0; i < 4; ++i)
                v[i] = el[(K * 16 + g * 4 + i) * NT + J * 16 + ln];
            BF[(K * 3 + J) * 64 + lane] = v;
        }
}

// ---------------------------------------------------------------------------
// Kernel 1: per (sample b, chunk c) compute M_c = prod_{t in chunk} (D_t E)
// via MFMA chain.  M kept in B-frag layout (== C layout for 16x16x16), so each
// step is: P = E*M (27 MFMA) -> row-scale by exp(emit)*s -> cvt_pk bf16 -> M.
// Lagged rescale s = 1/P00(prev step); log2 correction accumulated in Lc.
// Stores M^T (row j = column j of M) bf16 row-major + Lc.
// ---------------------------------------------------------------------------
__global__ void __launch_bounds__(64)
crf_phase1(const float* __restrict__ feat, const int* __restrict__ seqlen,
           void* ws) {
    const int c = blockIdx.x, b = blockIdx.y;
    const int t0 = c * LCH;
    const int L = seqlen[b];
    int n = L - t0;
    if (n <= 0) return;
    if (n > LCH) n = LCH;

    const int lane = threadIdx.x, ln = lane & 15, g = lane >> 4;
    __shared__ v4f flv[2 * 192];          // 2 quarter-buffers x 16 rows x 48 f32

    const u32x2* AF = (const u32x2*)((const char*)ws + TAF);
    const v4f*   BF = (const v4f*)((const char*)ws + TBF);

    s16x4 aw[3][3];
    #pragma unroll
    for (int I = 0; I < 3; ++I)
        #pragma unroll
        for (int K = 0; K < 3; ++K)
            aw[I][K] = __builtin_bit_cast(s16x4, AF[(I * 3 + K) * 64 + lane]);

    const float* frow0 = feat + ((size_t)b * SEQ + t0) * NT;

    // --- init M = D_{t0} E  (row k scaled by exp(emit_{t0}[k]))
    u32 mw[3][3][2];
    {
        v4f emx[3];
        #pragma unroll
        for (int K = 0; K < 3; ++K) {
            v4f e = *(const v4f*)(frow0 + K * 16 + g * 4);
            #pragma unroll
            for (int i = 0; i < 4; ++i) emx[K][i] = __expf(e[i]);
        }
        #pragma unroll
        for (int K = 0; K < 3; ++K)
            #pragma unroll
            for (int J = 0; J < 3; ++J) {
                v4f bf = BF[(K * 3 + J) * 64 + lane];
                mw[K][J][0] = pkbf(bf[0] * emx[K][0], bf[1] * emx[K][1]);
                mw[K][J][1] = pkbf(bf[2] * emx[K][2], bf[3] * emx[K][3]);
            }
    }

    // --- feature staging: reg-prefetch quarter -> LDS double-buffer
    v4f pf[3];
    #pragma unroll
    for (int m = 0; m < 3; ++m) pf[m] = ((const v4f*)frow0)[m * 64 + lane];
    #pragma unroll
    for (int m = 0; m < 3; ++m) flv[m * 64 + lane] = pf[m];          // buf 0 = q0
    #pragma unroll
    for (int m = 0; m < 3; ++m)
        pf[m] = ((const v4f*)(frow0 + 16 * NT))[m * 64 + lane];      // load q1

    float Lc = 0.f, s = 1.f, lg = 0.f;
    const v4f kz = {0.f, 0.f, 0.f, 0.f};

    for (int t = 1; t < n; ++t) {
        if ((t & 15) == 0) {
            const int q = t >> 4;
            #pragma unroll
            for (int m = 0; m < 3; ++m)
                flv[(q & 1) * 192 + m * 64 + lane] = pf[m];          // commit q
            if (q < 3) {
                #pragma unroll
                for (int m = 0; m < 3; ++m)
                    pf[m] = ((const v4f*)(frow0 + (q + 1) * 16 * NT))[m * 64 + lane];
            }
        }
        // row factors: exp(emit_t[row]) * s  (rows (l>>4)*4+i per tile-block K)
        v4f sp[3];
        {
            const int base = ((t >> 4) & 1) * 192 + (t & 15) * 12 + g;
            #pragma unroll
            for (int K = 0; K < 3; ++K) {
                v4f f = flv[base + K * 4];
                #pragma unroll
                for (int i = 0; i < 4; ++i) sp[K][i] = __expf(f[i]) * s;
            }
        }
        Lc += lg;

        v4f acc[3][3];
        #pragma unroll
        for (int I = 0; I < 3; ++I)
            #pragma unroll
            for (int J = 0; J < 3; ++J) {
                v4f a = mfma16(aw[I][0],
                    __builtin_bit_cast(s16x4, (u32x2){mw[0][J][0], mw[0][J][1]}), kz);
                a = mfma16(aw[I][1],
                    __builtin_bit_cast(s16x4, (u32x2){mw[1][J][0], mw[1][J][1]}), a);
                acc[I][J] = mfma16(aw[I][2],
                    __builtin_bit_cast(s16x4, (u32x2){mw[2][J][0], mw[2][J][1]}), a);
            }

        const float gn = rfl(acc[0][0][0]);      // raw P00 -> next-step scale
        #pragma unroll
        for (int K = 0; K < 3; ++K)
            #pragma unroll
            for (int J = 0; J < 3; ++J) {
                mw[K][J][0] = pkbf(acc[K][J][0] * sp[K][0], acc[K][J][1] * sp[K][1]);
                mw[K][J][1] = pkbf(acc[K][J][2] * sp[K][2], acc[K][J][3] * sp[K][3]);
            }
        s = __builtin_amdgcn_rcpf(gn);
        lg = __log2f(gn);
    }

    // --- store M^T bf16 (element M[kk][nn] -> byte 2*(nn*48+kk)) + scale
    char* wb = (char*)ws + TW + ((size_t)(b * NCH + c)) * 4608;
    #pragma unroll
    for (int K = 0; K < 3; ++K)
        #pragma unroll
        for (int J = 0; J < 3; ++J)
            #pragma unroll
            for (int r = 0; r < 2; ++r)
                *(u32*)(wb + 2 * ((J * 16 + ln) * NT + K * 16 + g * 4 + 2 * r)) =
                    mw[K][J][r];
    if (lane == 0)
        ((float*)((char*)ws + TSC))[b * NCH + c] = Lc;
}

// ---------------------------------------------------------------------------
// Kernel 2: per sample, u^T <- u^T * M_c for c = nb-1 .. 0 (reverse), lane j
// owns u[j]; M^T row j is contiguous bf16. out = ln2*(D + log2(u[START])).
// ---------------------------------------------------------------------------
__global__ void __launch_bounds__(64)
crf_phase2(const float* __restrict__ trans, const int* __restrict__ seqlen,
           const void* ws, float* __restrict__ out) {
    const int b = blockIdx.x;
    const int lane = threadIdx.x;
    const int j = (lane < NT) ? lane : (lane - 16);
    __shared__ v4f hs4[12];
    float* hs = (float*)hs4;

    const int L = seqlen[b];
    const int nb = (L + LCH - 1) / LCH;
    const float* sc = (const float*)((const char*)ws + TSC) + b * NCH;
    const char* wbase = (const char*)ws + TW + (size_t)b * NCH * 4608;

    float q = __expf(trans[END_TAG * NT + j]);   // u0 (exp(MIN)=0 handles col 47)
    float D = 0.f;

    for (int c = nb - 1; c >= 0; --c) {
        if (lane < NT) hs[lane] = q;
        v4f hq[12];
        #pragma unroll
        for (int k = 0; k < 12; ++k) hq[k] = hs4[k];
        const float h0 = hq[0][0];

        const u32x4* wr = (const u32x4*)(wbase + (size_t)c * 4608 + j * 96);
        v2f a = {0.f, 0.f};
        #pragma unroll
        for (int m = 0; m < 6; ++m) {
            u32x4 wv = wr[m];
            #pragma unroll
            for (int p = 0; p < 4; ++p) {
                const int i = 2 * (4 * m + p);
                u32 w = wv[p];
                v2f wp;
                wp.x = __builtin_bit_cast(float, w << 16);
                wp.y = __builtin_bit_cast(float, w & 0xffff0000u);
                v2f up = { hq[i >> 2][i & 3], hq[i >> 2][(i & 3) + 1] };
                a += wp * up;
            }
        }
        const float dot = a.x + a.y;
        q = dot * __builtin_amdgcn_rcpf(h0);
        D += __log2f(h0) + sc[c];
    }
    if (lane < NT) hs[lane] = q;
    if (lane == 0)
        out[b] = LN2f * (D + __log2f(hs[START_TAG]));
}

// ---------------------------------------------------------------------------
// Fallback: proven round-2 scalar kernel (used when ws too small)
// ---------------------------------------------------------------------------
__global__ void __launch_bounds__(64)
crf_scalar(const float* __restrict__ features, const float* __restrict__ transitions,
           const int* __restrict__ seq_len, float* __restrict__ out) {
    const int b = blockIdx.x;
    const int lane = threadIdx.x;
    const int j = (lane < NT) ? lane : (lane - 16);
    __shared__ v4f hs4[NT / 4];
    float* hs = (float*)hs4;

    v2f E2[NT / 2];
    {
        const v4f* trow = (const v4f*)(transitions + j * NT);
        #pragma unroll
        for (int k = 0; k < NT / 4; ++k) {
            v4f tv = trow[k];
            E2[2 * k].x = __expf(tv.x); E2[2 * k].y = __expf(tv.y);
            E2[2 * k + 1].x = __expf(tv.z); E2[2 * k + 1].y = __expf(tv.w);
        }
    }
    const float Eend = __expf(transitions[END_TAG * NT + j]);
    const int L = seq_len[b];
    const float* fbase = features + ((size_t)b * SEQ) * NT + j;

    float q = E2[START_TAG / 2].x * __expf(fbase[0]);
    float Clog2 = 0.0f;
    if (lane < NT) hs[lane] = q;

    float fb[8];
    #pragma unroll
    for (int u = 0; u < 8; ++u) {
        int tp = 1 + u;
        fb[u] = fbase[(size_t)(tp < SEQ ? tp : 0) * NT];
    }

    auto STEP = [&](float femit) {
        v4f hq[NT / 4];
        #pragma unroll
        for (int k = 0; k < NT / 4; ++k) hq[k] = hs4[k];
        float h0 = hq[0].x;
        float r = __builtin_amdgcn_rcpf(h0);
        float e = __expf(femit);
        float re = r * e;
        v2f a0 = {0.f, 0.f}, a1 = {0.f, 0.f};
        #pragma unroll
        for (int k = 0; k < NT / 4; ++k) {
            v2f lo = { hq[k].x, hq[k].y };
            v2f hi = { hq[k].z, hq[k].w };
            a0 += E2[2 * k] * lo;
            a1 += E2[2 * k + 1] * hi;
        }
        float d = (a0.x + a1.x) + (a0.y + a1.y);
        q = d * re;
        Clog2 += __log2f(h0);
        if (lane < NT) hs[lane] = q;
    };

    int t = 1;
    while (t + 8 <= L) {
        #pragma unroll
        for (int u = 0; u < 8; ++u) {
            STEP(fb[u]);
            int tp = t + u + 8;
            fb[u] = fbase[(size_t)(tp < SEQ ? tp : 0) * NT];
        }
        t += 8;
    }
    #pragma unroll
    for (int u = 0; u < 8; ++u)
        if (t + u < L) STEP(fb[u]);

    float term = (lane < NT) ? q * Eend : 0.0f;
    #pragma unroll
    for (int m = 32; m >= 1; m >>= 1) term += __shfl_xor(term, m, 64);
    if (lane == 0) out[b] = LN2f * (Clog2 + __log2f(term));
}

extern "C" void kernel_launch(void* const* d_in, const int* in_sizes, int n_in,
                              void* d_out, int out_size, void* d_ws, size_t ws_size,
                              hipStream_t stream) {
    const float* features    = (const float*)d_in[0];
    const float* transitions = (const float*)d_in[1];
    const int*   seqlen      = (const int*)d_in[2];
    float* out = (float*)d_out;

    const size_t need = (size_t)TW + (size_t)BATCH * NCH * 4608;
    if (ws_size >= need) {
        crf_setup<<<1, 64, 0, stream>>>(transitions, d_ws);
        crf_phase1<<<dim3(NCH, BATCH), 64, 0, stream>>>(features, seqlen, d_ws);
        crf_phase2<<<BATCH, 64, 0, stream>>>(transitions, seqlen, d_ws, out);
    } else {
        crf_scalar<<<BATCH, 64, 0, stream>>>(features, transitions, seqlen, out);
    }
}

// Round 4
// 160.042 us; speedup vs baseline: 15.2727x; 1.1403x over previous
//
#include <hip/hip_runtime.h>

#define BATCH 256
#define SEQ 2048
#define NT 48
#define START_TAG 46
#define END_TAG 47
#define LN2f 0.6931471805599453f

// ws layout
#define TAF 0          // A-frags of exp(trans) bf16: [9][64] x 8B   (4608 B)
#define TBF 4608       // B-frag exp(trans) f32:      [9][64] x 16B  (9216 B)
#define TSC 16384      // per-chunk log2 scales: [B][NCH] f32        (<=64 KiB)
#define TW  131072     // chunk matrices M^T bf16: [B][NCH][48][48]

typedef float v2f __attribute__((ext_vector_type(2)));
typedef float v4f __attribute__((ext_vector_type(4)));
typedef short s16x4 __attribute__((ext_vector_type(4)));
typedef unsigned int u32;
typedef u32 u32x2 __attribute__((ext_vector_type(2)));
typedef u32 u32x4 __attribute__((ext_vector_type(4)));

__device__ __forceinline__ u32 pkbf(float a, float b) {
    u32 r;
    asm("v_cvt_pk_bf16_f32 %0, %1, %2" : "=v"(r) : "v"(a), "v"(b));
    return r;
}

__device__ __forceinline__ float rfl(float x) {
    return __builtin_bit_cast(float,
        __builtin_amdgcn_readfirstlane(__builtin_bit_cast(int, x)));
}

#if defined(__has_builtin)
#if __has_builtin(__builtin_amdgcn_mfma_f32_16x16x16bf16_1k)
#define MFMA1K 1
#endif
#endif

__device__ __forceinline__ v4f mfma16(s16x4 a, s16x4 b, v4f c) {
#ifdef MFMA1K
    return __builtin_amdgcn_mfma_f32_16x16x16bf16_1k(a, b, c, 0, 0, 0);
#else
    v4f d;
    asm volatile("v_mfma_f32_16x16x16_bf16 %0, %1, %2, %3\n\ts_nop 7\n\ts_nop 7"
                 : "=v"(d) : "v"(a), "v"(b), "v"(c));
    return d;
#endif
}

// ---------------------------------------------------------------------------
// Kernel 0: build exp(trans) fragments once. 1 block x 64.
// A-frag (tile I,K): lane holds E[I*16+(l&15)][K*16+(l>>4)*4+i], i=0..3, bf16.
// B-frag (tile K,J): lane holds E[K*16+(l>>4)*4+i][J*16+(l&15)], f32.
// ---------------------------------------------------------------------------
__global__ void __launch_bounds__(64)
crf_setup(const float* __restrict__ trans, void* ws) {
    __shared__ float el[NT * NT];
    const int lane = threadIdx.x, ln = lane & 15, g = lane >> 4;
    #pragma unroll
    for (int m = 0; m < 36; ++m) {
        int idx = lane + 64 * m;
        el[idx] = __expf(trans[idx]);
    }
    u32x2* AF = (u32x2*)((char*)ws + TAF);
    v4f*   BF = (v4f*)((char*)ws + TBF);
    #pragma unroll
    for (int I = 0; I < 3; ++I)
        #pragma unroll
        for (int K = 0; K < 3; ++K) {
            const v4f ev = *(const v4f*)&el[(I * 16 + ln) * NT + K * 16 + g * 4];
            u32x2 w;
            w.x = pkbf(ev.x, ev.y);
            w.y = pkbf(ev.z, ev.w);
            AF[(I * 3 + K) * 64 + lane] = w;
        }
    #pragma unroll
    for (int K = 0; K < 3; ++K)
        #pragma unroll
        for (int J = 0; J < 3; ++J) {
            v4f v;
            #pragma unroll
            for (int i = 0; i < 4; ++i)
                v[i] = el[(K * 16 + g * 4 + i) * NT + J * 16 + ln];
            BF[(K * 3 + J) * 64 + lane] = v;
        }
}

// ---------------------------------------------------------------------------
// Kernel 1: per (sample b, chunk c): M_c = prod_{t in chunk} (D_t E) by MFMA
// chain; M kept in B-frag(==C) layout.  Per step: 27 MFMA; row-scale by
// prefetched exp(emit)*s (lagged 1/P00 rescale); cvt_pk -> bf16.
// mw typed s16x4 so B operands live as register pairs (no rebuild movs).
// ---------------------------------------------------------------------------
template<int LCH_, int NCH_>
__global__ void __launch_bounds__(64)
crf_phase1(const float* __restrict__ feat, const int* __restrict__ seqlen,
           void* __restrict__ ws) {
    const int b = blockIdx.x, c = blockIdx.y;
    const int t0 = c * LCH_;
    const int L = seqlen[b];
    int n = L - t0;
    if (n <= 0) return;
    if (n > LCH_) n = LCH_;

    const int lane = threadIdx.x, ln = lane & 15, g = lane >> 4;
    __shared__ v4f flv[(LCH_ + 1) * 12];   // [step][12 v4f] emissions (+1 pad)

    const u32x2* AF = (const u32x2*)((const char*)ws + TAF);
    const v4f*   BF = (const v4f*)((const char*)ws + TBF);

    s16x4 aw[3][3];
    #pragma unroll
    for (int I = 0; I < 3; ++I)
        #pragma unroll
        for (int K = 0; K < 3; ++K)
            aw[I][K] = __builtin_bit_cast(s16x4, AF[(I * 3 + K) * 64 + lane]);

    // stage the whole chunk's emissions (always in-bounds: t0+LCH_-1 < SEQ)
    const v4f* fg = (const v4f*)(feat + ((size_t)b * SEQ + t0) * NT);
    #pragma unroll
    for (int m = 0; m < (LCH_ * 12) / 64; ++m)
        flv[m * 64 + lane] = fg[m * 64 + lane];

    // init M = D_{t0} E  (row k scaled by exp(emit_{t0}[k]))
    s16x4 mw[3][3];
    {
        v4f emx[3];
        #pragma unroll
        for (int K = 0; K < 3; ++K) {
            v4f e = flv[K * 4 + g];
            #pragma unroll
            for (int i = 0; i < 4; ++i) emx[K][i] = __expf(e[i]);
        }
        #pragma unroll
        for (int K = 0; K < 3; ++K)
            #pragma unroll
            for (int J = 0; J < 3; ++J) {
                v4f sc = BF[(K * 3 + J) * 64 + lane] * emx[K];
                mw[K][J] = __builtin_bit_cast(s16x4,
                    (u32x2){pkbf(sc.x, sc.y), pkbf(sc.z, sc.w)});
            }
    }

    // prefetch exp(emissions) for t=1
    v4f ef[3];
    #pragma unroll
    for (int K = 0; K < 3; ++K) {
        v4f f = flv[12 + K * 4 + g];
        #pragma unroll
        for (int i = 0; i < 4; ++i) ef[K][i] = __expf(f[i]);
    }

    float Lc = 0.f, s = 1.f, lg = 0.f;
    const v4f kz = {0.f, 0.f, 0.f, 0.f};

    for (int t = 1; t < n; ++t) {
        v4f sp[3];
        #pragma unroll
        for (int K = 0; K < 3; ++K) sp[K] = ef[K] * s;   // v_pk_mul_f32
        Lc += lg;

        v4f acc[3][3];
        #pragma unroll
        for (int I = 0; I < 3; ++I)
            #pragma unroll
            for (int J = 0; J < 3; ++J) {
                v4f a = mfma16(aw[I][0], mw[0][J], kz);
                a     = mfma16(aw[I][1], mw[1][J], a);
                acc[I][J] = mfma16(aw[I][2], mw[2][J], a);
            }

        // prefetch next step's exps while MFMAs drain (chain-independent)
        {
            const int tb = (t + 1) * 12 + g;
            #pragma unroll
            for (int K = 0; K < 3; ++K) {
                v4f f = flv[tb + K * 4];
                #pragma unroll
                for (int i = 0; i < 4; ++i) ef[K][i] = __expf(f[i]);
            }
        }

        const float gn = rfl(acc[0][0].x);   // raw P00 -> next-step scale
        #pragma unroll
        for (int K = 0; K < 3; ++K)
            #pragma unroll
            for (int J = 0; J < 3; ++J) {
                v4f sc = acc[K][J] * sp[K];  // v_pk_mul_f32 x2
                mw[K][J] = __builtin_bit_cast(s16x4,
                    (u32x2){pkbf(sc.x, sc.y), pkbf(sc.z, sc.w)});
            }
        s  = __builtin_amdgcn_rcpf(gn);
        lg = __log2f(gn);
    }

    // store M^T bf16 (element M[kk][nn] -> byte 2*(nn*48+kk)) + scale
    char* wb = (char*)ws + TW + ((size_t)(b * NCH_ + c)) * 4608;
    #pragma unroll
    for (int K = 0; K < 3; ++K)
        #pragma unroll
        for (int J = 0; J < 3; ++J) {
            u32x2 w = __builtin_bit_cast(u32x2, mw[K][J]);
            *(u32*)(wb + 2 * ((J * 16 + ln) * NT + K * 16 + g * 4))     = w.x;
            *(u32*)(wb + 2 * ((J * 16 + ln) * NT + K * 16 + g * 4 + 2)) = w.y;
        }
    if (lane == 0)
        ((float*)((char*)ws + TSC))[b * NCH_ + c] = Lc;
}

// ---------------------------------------------------------------------------
// Kernel 2: per sample, u^T <- u^T * M_c for c = nb-1..0; lane j owns u[j];
// M^T row j contiguous bf16.  Next chunk's row is prefetched (double-buffer)
// to hide HBM/L2 latency on the sequential chain.
// ---------------------------------------------------------------------------
template<int LCH_, int NCH_>
__global__ void __launch_bounds__(64)
crf_phase2(const float* __restrict__ trans, const int* __restrict__ seqlen,
           const void* __restrict__ ws, float* __restrict__ out) {
    const int b = blockIdx.x;
    const int lane = threadIdx.x;
    const int j = (lane < NT) ? lane : (lane - 16);
    __shared__ v4f hs4[12];
    float* hs = (float*)hs4;

    const int L = seqlen[b];
    const int nb = (L + LCH_ - 1) / LCH_;
    const float* sc = (const float*)((const char*)ws + TSC) + b * NCH_;
    const char* wbase = (const char*)ws + TW + (size_t)b * NCH_ * 4608;

    float q = __expf(trans[END_TAG * NT + j]);   // u0 (exp(MIN)=0 -> col END)
    float D = 0.f;

    u32x4 buf[6];
    {
        const u32x4* wr = (const u32x4*)(wbase + (size_t)(nb - 1) * 4608 + j * 96);
        #pragma unroll
        for (int m = 0; m < 6; ++m) buf[m] = wr[m];
    }

    for (int c = nb - 1; c >= 0; --c) {
        u32x4 cur[6];
        #pragma unroll
        for (int m = 0; m < 6; ++m) cur[m] = buf[m];
        if (c > 0) {   // issue next chunk's loads early
            const u32x4* wr = (const u32x4*)(wbase + (size_t)(c - 1) * 4608 + j * 96);
            #pragma unroll
            for (int m = 0; m < 6; ++m) buf[m] = wr[m];
        }

        if (lane < NT) hs[lane] = q;
        v4f hq[12];
        #pragma unroll
        for (int k = 0; k < 12; ++k) hq[k] = hs4[k];
        const float h0 = hq[0][0];

        v2f a = {0.f, 0.f};
        #pragma unroll
        for (int m = 0; m < 6; ++m) {
            #pragma unroll
            for (int p = 0; p < 4; ++p) {
                const int i = 2 * (4 * m + p);
                u32 w = cur[m][p];
                v2f wp;
                wp.x = __builtin_bit_cast(float, w << 16);
                wp.y = __builtin_bit_cast(float, w & 0xffff0000u);
                v2f up = { hq[i >> 2][i & 3], hq[i >> 2][(i & 3) + 1] };
                a += wp * up;
            }
        }
        const float dot = a.x + a.y;
        q = dot * __builtin_amdgcn_rcpf(h0);
        D += __log2f(h0) + sc[c];
    }
    if (lane < NT) hs[lane] = q;
    if (lane == 0)
        out[b] = LN2f * (D + __log2f(hs[START_TAG]));
}

// ---------------------------------------------------------------------------
// Fallback: proven round-2 scalar kernel (ws too small)
// ---------------------------------------------------------------------------
__global__ void __launch_bounds__(64)
crf_scalar(const float* __restrict__ features, const float* __restrict__ transitions,
           const int* __restrict__ seq_len, float* __restrict__ out) {
    const int b = blockIdx.x;
    const int lane = threadIdx.x;
    const int j = (lane < NT) ? lane : (lane - 16);
    __shared__ v4f hs4[NT / 4];
    float* hs = (float*)hs4;

    v2f E2[NT / 2];
    {
        const v4f* trow = (const v4f*)(transitions + j * NT);
        #pragma unroll
        for (int k = 0; k < NT / 4; ++k) {
            v4f tv = trow[k];
            E2[2 * k].x = __expf(tv.x); E2[2 * k].y = __expf(tv.y);
            E2[2 * k + 1].x = __expf(tv.z); E2[2 * k + 1].y = __expf(tv.w);
        }
    }
    const float Eend = __expf(transitions[END_TAG * NT + j]);
    const int L = seq_len[b];
    const float* fbase = features + ((size_t)b * SEQ) * NT + j;

    float q = E2[START_TAG / 2].x * __expf(fbase[0]);
    float Clog2 = 0.0f;
    if (lane < NT) hs[lane] = q;

    float fb[8];
    #pragma unroll
    for (int u = 0; u < 8; ++u) {
        int tp = 1 + u;
        fb[u] = fbase[(size_t)(tp < SEQ ? tp : 0) * NT];
    }

    auto STEP = [&](float femit) {
        v4f hq[NT / 4];
        #pragma unroll
        for (int k = 0; k < NT / 4; ++k) hq[k] = hs4[k];
        float h0 = hq[0].x;
        float r = __builtin_amdgcn_rcpf(h0);
        float e = __expf(femit);
        float re = r * e;
        v2f a0 = {0.f, 0.f}, a1 = {0.f, 0.f};
        #pragma unroll
        for (int k = 0; k < NT / 4; ++k) {
            v2f lo = { hq[k].x, hq[k].y };
            v2f hi = { hq[k].z, hq[k].w };
            a0 += E2[2 * k] * lo;
            a1 += E2[2 * k + 1] * hi;
        }
        float d = (a0.x + a1.x) + (a0.y + a1.y);
        q = d * re;
        Clog2 += __log2f(h0);
        if (lane < NT) hs[lane] = q;
    };

    int t = 1;
    while (t + 8 <= L) {
        #pragma unroll
        for (int u = 0; u < 8; ++u) {
            STEP(fb[u]);
            int tp = t + u + 8;
            fb[u] = fbase[(size_t)(tp < SEQ ? tp : 0) * NT];
        }
        t += 8;
    }
    #pragma unroll
    for (int u = 0; u < 8; ++u)
        if (t + u < L) STEP(fb[u]);

    float term = (lane < NT) ? q * Eend : 0.0f;
    #pragma unroll
    for (int m = 32; m >= 1; m >>= 1) term += __shfl_xor(term, m, 64);
    if (lane == 0) out[b] = LN2f * (Clog2 + __log2f(term));
}

extern "C" void kernel_launch(void* const* d_in, const int* in_sizes, int n_in,
                              void* d_out, int out_size, void* d_ws, size_t ws_size,
                              hipStream_t stream) {
    const float* features    = (const float*)d_in[0];
    const float* transitions = (const float*)d_in[1];
    const int*   seqlen      = (const int*)d_in[2];
    float* out = (float*)d_out;

    const size_t need64 = (size_t)TW + (size_t)BATCH * 64 * 4608;   // ~75.6 MB
    const size_t need32 = (size_t)TW + (size_t)BATCH * 32 * 4608;   // ~37.9 MB
    if (ws_size >= need64) {
        crf_setup<<<1, 64, 0, stream>>>(transitions, d_ws);
        crf_phase1<32, 64><<<dim3(BATCH, 64), 64, 0, stream>>>(features, seqlen, d_ws);
        crf_phase2<32, 64><<<BATCH, 64, 0, stream>>>(transitions, seqlen, d_ws, out);
    } else if (ws_size >= need32) {
        crf_setup<<<1, 64, 0, stream>>>(transitions, d_ws);
        crf_phase1<64, 32><<<dim3(BATCH, 32), 64, 0, stream>>>(features, seqlen, d_ws);
        crf_phase2<64, 32><<<BATCH, 64, 0, stream>>>(transitions, seqlen, d_ws, out);
    } else {
        crf_scalar<<<BATCH, 64, 0, stream>>>(features, transitions, seqlen, out);
    }
}